// Round 4
// baseline (483.107 us; speedup 1.0000x reference)
//
#include <hip/hip_runtime.h>
#include <hip/hip_bf16.h>

#define NN 50000
#define NE 800000
#define DD 128
#define LN_EPS 1e-5f

typedef __bf16 bf16x8 __attribute__((ext_vector_type(8)));
typedef float f32x4 __attribute__((ext_vector_type(4)));

__device__ inline ushort f2bf_bits(float f) {
    union { __hip_bfloat16 h; ushort u; } c;
    c.h = __float2bfloat16(f);
    return c.u;
}

// ---------------- CSR build ----------------

__global__ void hist_kernel(const int* __restrict__ dst, int* __restrict__ counts) {
    int e = blockIdx.x * 256 + threadIdx.x;
    if (e < NE) atomicAdd(&counts[dst[e]], 1);
}

__global__ void scan_blocks(const int* __restrict__ counts, int* __restrict__ excl,
                            int* __restrict__ block_sums) {
    __shared__ int ws[5];
    int gid = blockIdx.x * 256 + threadIdx.x;
    int lane = threadIdx.x & 63, wid = threadIdx.x >> 6;
    int v = (gid < NN) ? counts[gid] : 0;
    int x = v;
#pragma unroll
    for (int off = 1; off < 64; off <<= 1) {
        int t = __shfl_up(x, off, 64);
        if (lane >= off) x += t;
    }
    if (lane == 63) ws[wid] = x;
    __syncthreads();
    if (threadIdx.x == 0) {
        int run = 0;
        for (int i = 0; i < 4; ++i) { int t = ws[i]; ws[i] = run; run += t; }
        ws[4] = run;
    }
    __syncthreads();
    if (gid < NN) excl[gid] = x - v + ws[wid];
    if (threadIdx.x == 0) block_sums[blockIdx.x] = ws[4];
}

__global__ void scan_sums_kernel(int* __restrict__ bsums, int nb) {
    __shared__ int ws[5];
    int lane = threadIdx.x & 63, wid = threadIdx.x >> 6;
    int v = (threadIdx.x < nb) ? bsums[threadIdx.x] : 0;
    int x = v;
#pragma unroll
    for (int off = 1; off < 64; off <<= 1) {
        int t = __shfl_up(x, off, 64);
        if (lane >= off) x += t;
    }
    if (lane == 63) ws[wid] = x;
    __syncthreads();
    if (threadIdx.x == 0) {
        int run = 0;
        for (int i = 0; i < 4; ++i) { int t = ws[i]; ws[i] = run; run += t; }
    }
    __syncthreads();
    if (threadIdx.x < nb) bsums[threadIdx.x] = x - v + ws[wid];
}

// row_ptr/next_pos/dinv + fused per-block degree histogram (64 capped bins)
__global__ void finalize_kernel(const int* __restrict__ excl, const int* __restrict__ bsums,
                                const int* __restrict__ counts, int* __restrict__ row_ptr,
                                int* __restrict__ next_pos, float* __restrict__ dinv,
                                int* __restrict__ deghist) {
    __shared__ int lh[64];
    if (threadIdx.x < 64) lh[threadIdx.x] = 0;
    __syncthreads();
    int gid = blockIdx.x * 256 + threadIdx.x;
    if (gid < NN) {
        int rp = excl[gid] + bsums[blockIdx.x];
        row_ptr[gid] = rp;
        next_pos[gid] = rp;
        int c = counts[gid];
        dinv[gid] = rsqrtf((float)c + 1.0f);
        atomicAdd(&lh[min(c, 63)], 1);
    }
    __syncthreads();
    if (threadIdx.x < 64) atomicAdd(&deghist[threadIdx.x], lh[threadIdx.x]);
    if (blockIdx.x == 0 && threadIdx.x == 0) row_ptr[NN] = NE;
}

// exclusive scan of the 64 degree bins -> dnext (one wave)
__global__ void binscan_kernel(const int* __restrict__ deghist, int* __restrict__ dnext) {
    int lane = threadIdx.x;
    int v = deghist[lane];
    int x = v;
#pragma unroll
    for (int off = 1; off < 64; off <<= 1) {
        int t = __shfl_up(x, off, 64);
        if (lane >= off) x += t;
    }
    dnext[lane] = x - v;
}

// degree-bucketed node permutation: waves get equal-degree nodes
__global__ void perm_kernel(const int* __restrict__ counts, int* __restrict__ dnext,
                            int* __restrict__ perm) {
    int i = blockIdx.x * 256 + threadIdx.x;
    if (i < NN) {
        int b = min(counts[i], 63);
        int pos = atomicAdd(&dnext[b], 1);
        perm[pos] = i;
    }
}

// fused 8B scatter: edge2[pos] = {src, bits(dinv[s]*dinv[d])} -> 1 line/edge
__global__ void fill_kernel(const int* __restrict__ src, const int* __restrict__ dst,
                            int* __restrict__ next_pos, const float* __restrict__ dinv,
                            int2* __restrict__ edge2) {
    int e = blockIdx.x * 256 + threadIdx.x;
    if (e < NE) {
        int s = src[e], d = dst[e];
        int pos = atomicAdd(&next_pos[d], 1);
        int2 o;
        o.x = s;
        o.y = __float_as_int(dinv[s] * dinv[d]);
        edge2[pos] = o;
    }
}

// ---------------- casts ----------------

__global__ void cast_kernel(const float* __restrict__ in, ushort* __restrict__ outb) {
    int i = blockIdx.x * 256 + threadIdx.x;  // over NN*64 float2 groups
    float2 v = ((const float2*)in)[i];
    ushort2 o;
    o.x = f2bf_bits(v.x);
    o.y = f2bf_bits(v.y);
    ((ushort2*)outb)[i] = o;
}

// Ws fp32 [l][k][n] -> Wt bf16 [l][n][k]
__global__ void wtcast_kernel(const float* __restrict__ W, ushort* __restrict__ Wt) {
    int i = blockIdx.x * 256 + threadIdx.x;  // 3*128*128 = 49152
    int l = i >> 14, k = (i >> 7) & 127, n = i & 127;
    Wt[l * 16384 + n * 128 + k] = f2bf_bits(W[i]);
}

// ---------------- per-layer: aggregate (pre-GEMM, linearity), bf16 gather ----------------
__device__ inline void accum8(float* acc, uint4 v, float w) {
    uint vv[4] = {v.x, v.y, v.z, v.w};
#pragma unroll
    for (int i = 0; i < 4; ++i) {
        float lo = __uint_as_float(vv[i] << 16);
        float hi = __uint_as_float(vv[i] & 0xffff0000u);
        acc[2 * i] = fmaf(w, lo, acc[2 * i]);
        acc[2 * i + 1] = fmaf(w, hi, acc[2 * i + 1]);
    }
}

// 4 nodes/wave (16 lanes x 16B each), degree-balanced via perm, x4 unrolled gather
__global__ __launch_bounds__(256) void agg_kernel(
    const ushort* __restrict__ curb, const int* __restrict__ row_ptr,
    const int2* __restrict__ edge2, const int* __restrict__ perm,
    const float* __restrict__ dinv, ushort* __restrict__ aggb) {
    int wavei = threadIdx.x >> 6;
    int lane = threadIdx.x & 63;
    int g = lane >> 4, t = lane & 15;
    int slot = blockIdx.x * 16 + wavei * 4 + g;  // grid 3125*16 = 50000 exact
    int node = perm[slot];
    int beg = row_ptr[node], end = row_ptr[node + 1];
    const uint4* cu4 = (const uint4*)curb;
    float acc[8] = {};
    int e = beg;
    for (; e + 4 <= end; e += 4) {
        int2 a0 = edge2[e + 0];
        int2 a1 = edge2[e + 1];
        int2 a2 = edge2[e + 2];
        int2 a3 = edge2[e + 3];
        uint4 v0 = cu4[a0.x * 16 + t];
        uint4 v1 = cu4[a1.x * 16 + t];
        uint4 v2 = cu4[a2.x * 16 + t];
        uint4 v3 = cu4[a3.x * 16 + t];
        accum8(acc, v0, __int_as_float(a0.y));
        accum8(acc, v1, __int_as_float(a1.y));
        accum8(acc, v2, __int_as_float(a2.y));
        accum8(acc, v3, __int_as_float(a3.y));
    }
    for (; e < end; ++e) {
        int2 a = edge2[e];
        accum8(acc, cu4[a.x * 16 + t], __int_as_float(a.y));
    }
    float di = dinv[node];
    accum8(acc, cu4[node * 16 + t], di * di);
    union { ushort us[8]; uint4 u; } pk;
#pragma unroll
    for (int i = 0; i < 8; ++i) pk.us[i] = f2bf_bits(acc[i]);
    ((uint4*)aggb)[node * 16 + t] = pk.u;
}

// ---------------- per-layer: MFMA GEMM + bias + LayerNorm + ReLU + residual ----------------
// Block 256 = 4 waves, 64 rows. LDS: Wt 128x17 uint4 + A 64x17 uint4 = 52224B -> 3 blocks/CU.
template <bool RES, bool FINAL>
__global__ __launch_bounds__(256) void gemm_ln_kernel(
    const ushort* __restrict__ aggb, const ushort* __restrict__ Wt,
    const float* __restrict__ bias, const float* __restrict__ gamma,
    const float* __restrict__ beta, ushort* __restrict__ featb, float* __restrict__ out) {
    __shared__ uint4 sB[128 * 17];
    __shared__ uint4 sA[64 * 17];

    const uint4* Wg = (const uint4*)Wt;
    for (int i = threadIdx.x; i < 2048; i += 256) sB[(i >> 4) * 17 + (i & 15)] = Wg[i];

    int row0 = blockIdx.x * 64;
    int nrows = min(64, NN - row0);
    const uint4* Ag = (const uint4*)(aggb + (size_t)row0 * DD);
    for (int i = threadIdx.x; i < nrows * 16; i += 256) sA[(i >> 4) * 17 + (i & 15)] = Ag[i];
    for (int i = nrows * 16 + threadIdx.x; i < 64 * 16; i += 256)
        sA[(i >> 4) * 17 + (i & 15)] = make_uint4(0, 0, 0, 0);
    __syncthreads();

    int w = threadIdx.x >> 6, lane = threadIdx.x & 63;
    int q = lane >> 4, m = lane & 15;

    f32x4 acc[8];
#pragma unroll
    for (int t = 0; t < 8; ++t) acc[t] = (f32x4){0.f, 0.f, 0.f, 0.f};

#pragma unroll
    for (int kk = 0; kk < 4; ++kk) {
        bf16x8 af = *(const bf16x8*)&sA[(16 * w + m) * 17 + kk * 4 + q];
#pragma unroll
        for (int t = 0; t < 8; ++t) {
            bf16x8 bf = *(const bf16x8*)&sB[(16 * t + m) * 17 + kk * 4 + q];
            acc[t] = __builtin_amdgcn_mfma_f32_16x16x32_bf16(af, bf, acc[t], 0, 0, 0);
        }
    }

    float s1[4] = {0.f, 0.f, 0.f, 0.f}, s2[4] = {0.f, 0.f, 0.f, 0.f};
#pragma unroll
    for (int t = 0; t < 8; ++t) {
        float b = bias[16 * t + m];
#pragma unroll
        for (int r = 0; r < 4; ++r) {
            float v = acc[t][r] + b;
            acc[t][r] = v;
            s1[r] += v;
            s2[r] += v * v;
        }
    }
#pragma unroll
    for (int off = 1; off <= 8; off <<= 1) {
#pragma unroll
        for (int r = 0; r < 4; ++r) {
            s1[r] += __shfl_xor(s1[r], off, 64);
            s2[r] += __shfl_xor(s2[r], off, 64);
        }
    }
    float mu[4], rstd[4];
#pragma unroll
    for (int r = 0; r < 4; ++r) {
        mu[r] = s1[r] * (1.f / 128.f);
        float var = s2[r] * (1.f / 128.f) - mu[r] * mu[r];
        rstd[r] = rsqrtf(var + LN_EPS);
    }
    int rowbase = row0 + 16 * w + q * 4;
#pragma unroll
    for (int t = 0; t < 8; ++t) {
        int col = 16 * t + m;
        float ga = gamma[col], be = beta[col];
#pragma unroll
        for (int r = 0; r < 4; ++r) {
            int row = rowbase + r;
            float o = fmaxf((acc[t][r] - mu[r]) * rstd[r] * ga + be, 0.f);
            if (row < NN) {
                size_t idx = (size_t)row * DD + col;
                if (RES) o += __uint_as_float(((uint)featb[idx]) << 16);
                if (FINAL) out[idx] = o;
                else featb[idx] = f2bf_bits(o);
            }
        }
    }
}

// ---------------- launch ----------------

extern "C" void kernel_launch(void* const* d_in, const int* in_sizes, int n_in,
                              void* d_out, int out_size, void* d_ws, size_t ws_size,
                              hipStream_t stream) {
    const float* x = (const float*)d_in[0];
    const int* edge = (const int*)d_in[1];
    const float* Ws = (const float*)d_in[2];
    const float* bs = (const float*)d_in[3];
    const float* gs = (const float*)d_in[4];
    const float* bes = (const float*)d_in[5];
    float* out = (float*)d_out;
    const int* src = edge;
    const int* dst = edge + NE;

    char* p = (char*)d_ws;
    int* counts = (int*)p;      p += (size_t)NN * 4;
    int* deghist = (int*)p;     p += 64 * 4;   // zeroed together with counts
    int* dnext = (int*)p;       p += 64 * 4;
    int* excl = (int*)p;        p += (size_t)NN * 4;
    int* bsums = (int*)p;       p += 256 * 4;
    int* row_ptr = (int*)p;     p += (size_t)(NN + 4) * 4;
    int* next_pos = (int*)p;    p += (size_t)NN * 4;
    float* dinv = (float*)p;    p += (size_t)NN * 4;
    int* perm = (int*)p;        p += (size_t)NN * 4;
    int2* edge2 = (int2*)p;     p += (size_t)NE * 8;
    ushort* aggb = (ushort*)p;  p += (size_t)NN * DD * 2;
    ushort* featb = (ushort*)p; p += (size_t)NN * DD * 2;
    ushort* Wt = (ushort*)p;    p += (size_t)3 * DD * DD * 2;

    hipMemsetAsync(counts, 0, ((size_t)NN + 64) * 4, stream);  // counts + deghist
    hist_kernel<<<NE / 256, 256, 0, stream>>>(dst, counts);
    scan_blocks<<<196, 256, 0, stream>>>(counts, excl, bsums);
    scan_sums_kernel<<<1, 256, 0, stream>>>(bsums, 196);
    finalize_kernel<<<196, 256, 0, stream>>>(excl, bsums, counts, row_ptr, next_pos, dinv,
                                             deghist);
    binscan_kernel<<<1, 64, 0, stream>>>(deghist, dnext);
    perm_kernel<<<196, 256, 0, stream>>>(counts, dnext, perm);
    fill_kernel<<<NE / 256, 256, 0, stream>>>(src, dst, next_pos, dinv, edge2);

    wtcast_kernel<<<192, 256, 0, stream>>>(Ws, Wt);
    cast_kernel<<<NN * 64 / 256, 256, 0, stream>>>(x, featb);

    int gemm_grid = (NN + 63) / 64;  // 782
    for (int l = 0; l < 3; ++l) {
        agg_kernel<<<NN / 16, 256, 0, stream>>>(featb, row_ptr, edge2, perm, dinv, aggb);
        const ushort* Wl = Wt + (size_t)l * DD * DD;
        const float* bl = bs + l * DD;
        const float* gl = gs + l * DD;
        const float* bel = bes + l * DD;
        if (l == 0)
            gemm_ln_kernel<false, false><<<gemm_grid, 256, 0, stream>>>(
                aggb, Wl, bl, gl, bel, featb, out);
        else if (l == 1)
            gemm_ln_kernel<true, false><<<gemm_grid, 256, 0, stream>>>(
                aggb, Wl, bl, gl, bel, featb, out);
        else
            gemm_ln_kernel<true, true><<<gemm_grid, 256, 0, stream>>>(
                aggb, Wl, bl, gl, bel, featb, out);
    }
}

// Round 5
// 387.222 us; speedup vs baseline: 1.2476x; 1.2476x over previous
//
#include <hip/hip_runtime.h>
#include <hip/hip_bf16.h>

#define NN 50000
#define NE 800000
#define DD 128
#define NB 196           // ceil(NN/256)
#define PH (64 * NB)     // flat bin-major block-histogram size = 12544
#define LN_EPS 1e-5f

typedef __bf16 bf16x8 __attribute__((ext_vector_type(8)));
typedef float f32x4 __attribute__((ext_vector_type(4)));

__device__ inline ushort f2bf_bits(float f) {
    union { __hip_bfloat16 h; ushort u; } c;
    c.h = __float2bfloat16(f);
    return c.u;
}

// ---------------- CSR build ----------------

__global__ void hist_kernel(const int* __restrict__ dst, int* __restrict__ counts) {
    int e = blockIdx.x * 256 + threadIdx.x;
    if (e < NE) atomicAdd(&counts[dst[e]], 1);
}

__global__ void scan_blocks(const int* __restrict__ counts, int* __restrict__ excl,
                            int* __restrict__ block_sums) {
    __shared__ int ws[5];
    int gid = blockIdx.x * 256 + threadIdx.x;
    int lane = threadIdx.x & 63, wid = threadIdx.x >> 6;
    int v = (gid < NN) ? counts[gid] : 0;
    int x = v;
#pragma unroll
    for (int off = 1; off < 64; off <<= 1) {
        int t = __shfl_up(x, off, 64);
        if (lane >= off) x += t;
    }
    if (lane == 63) ws[wid] = x;
    __syncthreads();
    if (threadIdx.x == 0) {
        int run = 0;
        for (int i = 0; i < 4; ++i) { int t = ws[i]; ws[i] = run; run += t; }
        ws[4] = run;
    }
    __syncthreads();
    if (gid < NN) excl[gid] = x - v + ws[wid];
    if (threadIdx.x == 0) block_sums[blockIdx.x] = ws[4];
}

__global__ void scan_sums_kernel(int* __restrict__ bsums, int nb) {
    __shared__ int ws[5];
    int lane = threadIdx.x & 63, wid = threadIdx.x >> 6;
    int v = (threadIdx.x < nb) ? bsums[threadIdx.x] : 0;
    int x = v;
#pragma unroll
    for (int off = 1; off < 64; off <<= 1) {
        int t = __shfl_up(x, off, 64);
        if (lane >= off) x += t;
    }
    if (lane == 63) ws[wid] = x;
    __syncthreads();
    if (threadIdx.x == 0) {
        int run = 0;
        for (int i = 0; i < 4; ++i) { int t = ws[i]; ws[i] = run; run += t; }
    }
    __syncthreads();
    if (threadIdx.x < nb) bsums[threadIdx.x] = x - v + ws[wid];
}

__global__ void finalize_kernel(const int* __restrict__ excl, const int* __restrict__ bsums,
                                const int* __restrict__ counts, int* __restrict__ row_ptr,
                                int* __restrict__ next_pos, float* __restrict__ dinv) {
    int gid = blockIdx.x * 256 + threadIdx.x;
    if (gid < NN) {
        int rp = excl[gid] + bsums[blockIdx.x];
        row_ptr[gid] = rp;
        next_pos[gid] = rp;
        dinv[gid] = rsqrtf((float)counts[gid] + 1.0f);
    }
    if (blockIdx.x == 0 && threadIdx.x == 0) row_ptr[NN] = NE;
}

// ---- degree-bucketed permutation via counting sort (no contended global atomics) ----

// per-block LDS histogram of 64 capped degree bins -> bin-major bh[b*NB + blk]
__global__ void blockhist_kernel(const int* __restrict__ counts, int* __restrict__ bh) {
    __shared__ int lh[64];
    if (threadIdx.x < 64) lh[threadIdx.x] = 0;
    __syncthreads();
    int gid = blockIdx.x * 256 + threadIdx.x;
    if (gid < NN) atomicAdd(&lh[min(counts[gid], 63)], 1);
    __syncthreads();
    if (threadIdx.x < 64) bh[threadIdx.x * NB + blockIdx.x] = lh[threadIdx.x];
}

// in-place exclusive scan of the 12544-element bin-major array (single block).
// scanned value at (b,blk) = global_bin_start[b] + sum_{blk'<blk} hist[b][blk'].
__global__ __launch_bounds__(1024) void permscan_kernel(int* __restrict__ bh) {
    __shared__ int wsum[16];
    const int CH = 13;  // 1024*13 = 13312 >= 12544
    int tid = threadIdx.x;
    int base = tid * CH;
    int vals[CH];
    int s = 0;
#pragma unroll
    for (int i = 0; i < CH; ++i) {
        int idx = base + i;
        int v = (idx < PH) ? bh[idx] : 0;
        vals[i] = s;
        s += v;
    }
    int lane = tid & 63, wid = tid >> 6;
    int x = s;
#pragma unroll
    for (int off = 1; off < 64; off <<= 1) {
        int t = __shfl_up(x, off, 64);
        if (lane >= off) x += t;
    }
    if (lane == 63) wsum[wid] = x;
    __syncthreads();
    if (tid == 0) {
        int run = 0;
        for (int i = 0; i < 16; ++i) { int t = wsum[i]; wsum[i] = run; run += t; }
    }
    __syncthreads();
    int texcl = x - s + wsum[wid];
#pragma unroll
    for (int i = 0; i < CH; ++i) {
        int idx = base + i;
        if (idx < PH) bh[idx] = texcl + vals[i];
    }
}

// scatter: local rank via LDS atomics (64 banks, cheap), position from scanned bh
__global__ void permscatter_kernel(const int* __restrict__ counts, const int* __restrict__ bh,
                                   int* __restrict__ perm) {
    __shared__ int lh[64];
    __shared__ int lbase[64];
    if (threadIdx.x < 64) {
        lh[threadIdx.x] = 0;
        lbase[threadIdx.x] = bh[threadIdx.x * NB + blockIdx.x];
    }
    __syncthreads();
    int gid = blockIdx.x * 256 + threadIdx.x;
    if (gid < NN) {
        int b = min(counts[gid], 63);
        int r = atomicAdd(&lh[b], 1);
        perm[lbase[b] + r] = gid;
    }
}

// fused 8B scatter: edge2[pos] = {src, bits(dinv[s]*dinv[d])} -> 1 line/edge
__global__ void fill_kernel(const int* __restrict__ src, const int* __restrict__ dst,
                            int* __restrict__ next_pos, const float* __restrict__ dinv,
                            int2* __restrict__ edge2) {
    int e = blockIdx.x * 256 + threadIdx.x;
    if (e < NE) {
        int s = src[e], d = dst[e];
        int pos = atomicAdd(&next_pos[d], 1);
        int2 o;
        o.x = s;
        o.y = __float_as_int(dinv[s] * dinv[d]);
        edge2[pos] = o;
    }
}

// ---------------- casts ----------------

__global__ void cast_kernel(const float* __restrict__ in, ushort* __restrict__ outb) {
    int i = blockIdx.x * 256 + threadIdx.x;
    float2 v = ((const float2*)in)[i];
    ushort2 o;
    o.x = f2bf_bits(v.x);
    o.y = f2bf_bits(v.y);
    ((ushort2*)outb)[i] = o;
}

__global__ void wtcast_kernel(const float* __restrict__ W, ushort* __restrict__ Wt) {
    int i = blockIdx.x * 256 + threadIdx.x;  // 3*128*128 = 49152
    int l = i >> 14, k = (i >> 7) & 127, n = i & 127;
    Wt[l * 16384 + n * 128 + k] = f2bf_bits(W[i]);
}

// ---------------- per-layer: aggregate (pre-GEMM, linearity), bf16 gather ----------------
__device__ inline void accum8(float* acc, uint4 v, float w) {
    uint vv[4] = {v.x, v.y, v.z, v.w};
#pragma unroll
    for (int i = 0; i < 4; ++i) {
        float lo = __uint_as_float(vv[i] << 16);
        float hi = __uint_as_float(vv[i] & 0xffff0000u);
        acc[2 * i] = fmaf(w, lo, acc[2 * i]);
        acc[2 * i + 1] = fmaf(w, hi, acc[2 * i + 1]);
    }
}

// 4 nodes/wave (16 lanes x 16B each), degree-balanced via perm, x4 unrolled gather
__global__ __launch_bounds__(256) void agg_kernel(
    const ushort* __restrict__ curb, const int* __restrict__ row_ptr,
    const int2* __restrict__ edge2, const int* __restrict__ perm,
    const float* __restrict__ dinv, ushort* __restrict__ aggb) {
    int wavei = threadIdx.x >> 6;
    int lane = threadIdx.x & 63;
    int g = lane >> 4, t = lane & 15;
    int slot = blockIdx.x * 16 + wavei * 4 + g;  // grid 3125*16 = 50000 exact
    int node = perm[slot];
    int beg = row_ptr[node], end = row_ptr[node + 1];
    const uint4* cu4 = (const uint4*)curb;
    float acc[8] = {};
    int e = beg;
    for (; e + 4 <= end; e += 4) {
        int2 a0 = edge2[e + 0];
        int2 a1 = edge2[e + 1];
        int2 a2 = edge2[e + 2];
        int2 a3 = edge2[e + 3];
        uint4 v0 = cu4[a0.x * 16 + t];
        uint4 v1 = cu4[a1.x * 16 + t];
        uint4 v2 = cu4[a2.x * 16 + t];
        uint4 v3 = cu4[a3.x * 16 + t];
        accum8(acc, v0, __int_as_float(a0.y));
        accum8(acc, v1, __int_as_float(a1.y));
        accum8(acc, v2, __int_as_float(a2.y));
        accum8(acc, v3, __int_as_float(a3.y));
    }
    for (; e < end; ++e) {
        int2 a = edge2[e];
        accum8(acc, cu4[a.x * 16 + t], __int_as_float(a.y));
    }
    float di = dinv[node];
    accum8(acc, cu4[node * 16 + t], di * di);
    union { ushort us[8]; uint4 u; } pk;
#pragma unroll
    for (int i = 0; i < 8; ++i) pk.us[i] = f2bf_bits(acc[i]);
    ((uint4*)aggb)[node * 16 + t] = pk.u;
}

// ---------------- per-layer: MFMA GEMM + bias + LayerNorm + ReLU + residual ----------------
// Block 256 = 4 waves, 64 rows. LDS: Wt 128x17 uint4 + A 64x17 uint4 = 52224B -> 3 blocks/CU.
template <bool RES, bool FINAL>
__global__ __launch_bounds__(256) void gemm_ln_kernel(
    const ushort* __restrict__ aggb, const ushort* __restrict__ Wt,
    const float* __restrict__ bias, const float* __restrict__ gamma,
    const float* __restrict__ beta, ushort* __restrict__ featb, float* __restrict__ out) {
    __shared__ uint4 sB[128 * 17];
    __shared__ uint4 sA[64 * 17];

    const uint4* Wg = (const uint4*)Wt;
    for (int i = threadIdx.x; i < 2048; i += 256) sB[(i >> 4) * 17 + (i & 15)] = Wg[i];

    int row0 = blockIdx.x * 64;
    int nrows = min(64, NN - row0);
    const uint4* Ag = (const uint4*)(aggb + (size_t)row0 * DD);
    for (int i = threadIdx.x; i < nrows * 16; i += 256) sA[(i >> 4) * 17 + (i & 15)] = Ag[i];
    for (int i = nrows * 16 + threadIdx.x; i < 64 * 16; i += 256)
        sA[(i >> 4) * 17 + (i & 15)] = make_uint4(0, 0, 0, 0);
    __syncthreads();

    int w = threadIdx.x >> 6, lane = threadIdx.x & 63;
    int q = lane >> 4, m = lane & 15;

    f32x4 acc[8];
#pragma unroll
    for (int t = 0; t < 8; ++t) acc[t] = (f32x4){0.f, 0.f, 0.f, 0.f};

#pragma unroll
    for (int kk = 0; kk < 4; ++kk) {
        bf16x8 af = *(const bf16x8*)&sA[(16 * w + m) * 17 + kk * 4 + q];
#pragma unroll
        for (int t = 0; t < 8; ++t) {
            bf16x8 bf = *(const bf16x8*)&sB[(16 * t + m) * 17 + kk * 4 + q];
            acc[t] = __builtin_amdgcn_mfma_f32_16x16x32_bf16(af, bf, acc[t], 0, 0, 0);
        }
    }

    float s1[4] = {0.f, 0.f, 0.f, 0.f}, s2[4] = {0.f, 0.f, 0.f, 0.f};
#pragma unroll
    for (int t = 0; t < 8; ++t) {
        float b = bias[16 * t + m];
#pragma unroll
        for (int r = 0; r < 4; ++r) {
            float v = acc[t][r] + b;
            acc[t][r] = v;
            s1[r] += v;
            s2[r] += v * v;
        }
    }
#pragma unroll
    for (int off = 1; off <= 8; off <<= 1) {
#pragma unroll
        for (int r = 0; r < 4; ++r) {
            s1[r] += __shfl_xor(s1[r], off, 64);
            s2[r] += __shfl_xor(s2[r], off, 64);
        }
    }
    float mu[4], rstd[4];
#pragma unroll
    for (int r = 0; r < 4; ++r) {
        mu[r] = s1[r] * (1.f / 128.f);
        float var = s2[r] * (1.f / 128.f) - mu[r] * mu[r];
        rstd[r] = rsqrtf(var + LN_EPS);
    }
    int rowbase = row0 + 16 * w + q * 4;
#pragma unroll
    for (int t = 0; t < 8; ++t) {
        int col = 16 * t + m;
        float ga = gamma[col], be = beta[col];
#pragma unroll
        for (int r = 0; r < 4; ++r) {
            int row = rowbase + r;
            float o = fmaxf((acc[t][r] - mu[r]) * rstd[r] * ga + be, 0.f);
            if (row < NN) {
                size_t idx = (size_t)row * DD + col;
                if (RES) o += __uint_as_float(((uint)featb[idx]) << 16);
                if (FINAL) out[idx] = o;
                else featb[idx] = f2bf_bits(o);
            }
        }
    }
}

// ---------------- launch ----------------

extern "C" void kernel_launch(void* const* d_in, const int* in_sizes, int n_in,
                              void* d_out, int out_size, void* d_ws, size_t ws_size,
                              hipStream_t stream) {
    const float* x = (const float*)d_in[0];
    const int* edge = (const int*)d_in[1];
    const float* Ws = (const float*)d_in[2];
    const float* bs = (const float*)d_in[3];
    const float* gs = (const float*)d_in[4];
    const float* bes = (const float*)d_in[5];
    float* out = (float*)d_out;
    const int* src = edge;
    const int* dst = edge + NE;

    char* p = (char*)d_ws;
    int* counts = (int*)p;      p += (size_t)NN * 4;
    int* excl = (int*)p;        p += (size_t)NN * 4;
    int* bsums = (int*)p;       p += 256 * 4;
    int* bh = (int*)p;          p += (size_t)PH * 4;
    int* row_ptr = (int*)p;     p += (size_t)(NN + 4) * 4;
    int* next_pos = (int*)p;    p += (size_t)NN * 4;
    float* dinv = (float*)p;    p += (size_t)NN * 4;
    int* perm = (int*)p;        p += (size_t)NN * 4;
    int2* edge2 = (int2*)p;     p += (size_t)NE * 8;
    ushort* aggb = (ushort*)p;  p += (size_t)NN * DD * 2;
    ushort* featb = (ushort*)p; p += (size_t)NN * DD * 2;
    ushort* Wt = (ushort*)p;    p += (size_t)3 * DD * DD * 2;

    hipMemsetAsync(counts, 0, (size_t)NN * 4, stream);
    hist_kernel<<<NE / 256, 256, 0, stream>>>(dst, counts);
    scan_blocks<<<NB, 256, 0, stream>>>(counts, excl, bsums);
    scan_sums_kernel<<<1, 256, 0, stream>>>(bsums, NB);
    finalize_kernel<<<NB, 256, 0, stream>>>(excl, bsums, counts, row_ptr, next_pos, dinv);
    blockhist_kernel<<<NB, 256, 0, stream>>>(counts, bh);
    permscan_kernel<<<1, 1024, 0, stream>>>(bh);
    permscatter_kernel<<<NB, 256, 0, stream>>>(counts, bh, perm);
    fill_kernel<<<NE / 256, 256, 0, stream>>>(src, dst, next_pos, dinv, edge2);

    wtcast_kernel<<<192, 256, 0, stream>>>(Ws, Wt);
    cast_kernel<<<NN * 64 / 256, 256, 0, stream>>>(x, featb);

    int gemm_grid = (NN + 63) / 64;  // 782
    for (int l = 0; l < 3; ++l) {
        agg_kernel<<<NN / 16, 256, 0, stream>>>(featb, row_ptr, edge2, perm, dinv, aggb);
        const ushort* Wl = Wt + (size_t)l * DD * DD;
        const float* bl = bs + l * DD;
        const float* gl = gs + l * DD;
        const float* bel = bes + l * DD;
        if (l == 0)
            gemm_ln_kernel<false, false><<<gemm_grid, 256, 0, stream>>>(
                aggb, Wl, bl, gl, bel, featb, out);
        else if (l == 1)
            gemm_ln_kernel<true, false><<<gemm_grid, 256, 0, stream>>>(
                aggb, Wl, bl, gl, bel, featb, out);
        else
            gemm_ln_kernel<true, true><<<gemm_grid, 256, 0, stream>>>(
                aggb, Wl, bl, gl, bel, featb, out);
    }
}

// Round 6
// 372.827 us; speedup vs baseline: 1.2958x; 1.0386x over previous
//
#include <hip/hip_runtime.h>
#include <hip/hip_bf16.h>

#define NN 50000
#define NE 800000
#define DD 128
#define NB 196             // ceil(NN/256)
#define NCH 8              // source chunks (1.6 MB bf16 slice each)
#define CHSZ 6250          // NN / NCH
#define NC2 (NN * NCH)     // per-(node,chunk) bins = 400000
#define NSB 391            // ceil(NC2/1024)
#define PH (64 * NB)       // degree-bucket histogram size = 12544
#define LN_EPS 1e-5f

typedef __bf16 bf16x8 __attribute__((ext_vector_type(8)));
typedef float f32x4 __attribute__((ext_vector_type(4)));

__device__ inline ushort f2bf_bits(float f) {
    union { __hip_bfloat16 h; ushort u; } c;
    c.h = __float2bfloat16(f);
    return c.u;
}

// ---------------- CSR build (chunk-ordered rows) ----------------

// per-(dst, src-chunk) histogram
__global__ void hist_kernel(const int* __restrict__ src, const int* __restrict__ dst,
                            int* __restrict__ counts2) {
    int e = blockIdx.x * 256 + threadIdx.x;
    if (e < NE) {
        int s = src[e], d = dst[e];
        atomicAdd(&counts2[d * NCH + s / CHSZ], 1);
    }
}

// level-0 scan over NC2 elements, 1024 threads/block, in-place; emits block sums
__global__ __launch_bounds__(1024) void scan1024_blocks(int* __restrict__ data,
                                                        int* __restrict__ bsums) {
    __shared__ int ws[16];
    int gid = blockIdx.x * 1024 + threadIdx.x;
    int lane = threadIdx.x & 63, wid = threadIdx.x >> 6;
    int v = (gid < NC2) ? data[gid] : 0;
    int x = v;
#pragma unroll
    for (int off = 1; off < 64; off <<= 1) {
        int t = __shfl_up(x, off, 64);
        if (lane >= off) x += t;
    }
    if (lane == 63) ws[wid] = x;
    __syncthreads();
    if (threadIdx.x == 0) {
        int run = 0;
        for (int i = 0; i < 16; ++i) { int t = ws[i]; ws[i] = run; run += t; }
        bsums[blockIdx.x] = run;
    }
    __syncthreads();
    if (gid < NC2) data[gid] = x - v + ws[wid];
}

// level-1: single block scans the 391 block sums
__global__ __launch_bounds__(1024) void scan_sums1024(int* __restrict__ bsums, int nb) {
    __shared__ int ws[16];
    int tid = threadIdx.x;
    int lane = tid & 63, wid = tid >> 6;
    int v = (tid < nb) ? bsums[tid] : 0;
    int x = v;
#pragma unroll
    for (int off = 1; off < 64; off <<= 1) {
        int t = __shfl_up(x, off, 64);
        if (lane >= off) x += t;
    }
    if (lane == 63) ws[wid] = x;
    __syncthreads();
    if (tid == 0) {
        int run = 0;
        for (int i = 0; i < 16; ++i) { int t = ws[i]; ws[i] = run; run += t; }
    }
    __syncthreads();
    if (tid < nb) bsums[tid] = x - v + ws[wid];
}

// absolute cursors, row_ptr, degree, dinv
__global__ void finalize_kernel(const int* __restrict__ excl2, const int* __restrict__ bsums,
                                int* __restrict__ row_ptr, int* __restrict__ next_pos2,
                                float* __restrict__ dinv, int* __restrict__ degarr) {
    int d = blockIdx.x * 256 + threadIdx.x;
    if (d < NN) {
        int base = d * NCH;
        int p0 = excl2[base] + bsums[base >> 10];
#pragma unroll
        for (int c = 0; c < NCH; ++c) {
            int idx = base + c;
            next_pos2[idx] = excl2[idx] + bsums[idx >> 10];
        }
        int nxt = (d == NN - 1) ? NE : excl2[base + NCH] + bsums[(base + NCH) >> 10];
        int deg = nxt - p0;
        row_ptr[d] = p0;
        dinv[d] = rsqrtf((float)deg + 1.0f);
        degarr[d] = deg;
    }
    if (blockIdx.x == 0 && threadIdx.x == 0) row_ptr[NN] = NE;
}

// ---- degree-bucketed permutation via counting sort ----

__global__ void blockhist_kernel(const int* __restrict__ degarr, int* __restrict__ bh) {
    __shared__ int lh[64];
    if (threadIdx.x < 64) lh[threadIdx.x] = 0;
    __syncthreads();
    int gid = blockIdx.x * 256 + threadIdx.x;
    if (gid < NN) atomicAdd(&lh[min(degarr[gid], 63)], 1);
    __syncthreads();
    if (threadIdx.x < 64) bh[threadIdx.x * NB + blockIdx.x] = lh[threadIdx.x];
}

__global__ __launch_bounds__(1024) void permscan_kernel(int* __restrict__ bh) {
    __shared__ int wsum[16];
    const int CH = 13;  // 1024*13 = 13312 >= 12544
    int tid = threadIdx.x;
    int base = tid * CH;
    int vals[CH];
    int s = 0;
#pragma unroll
    for (int i = 0; i < CH; ++i) {
        int idx = base + i;
        int v = (idx < PH) ? bh[idx] : 0;
        vals[i] = s;
        s += v;
    }
    int lane = tid & 63, wid = tid >> 6;
    int x = s;
#pragma unroll
    for (int off = 1; off < 64; off <<= 1) {
        int t = __shfl_up(x, off, 64);
        if (lane >= off) x += t;
    }
    if (lane == 63) wsum[wid] = x;
    __syncthreads();
    if (tid == 0) {
        int run = 0;
        for (int i = 0; i < 16; ++i) { int t = wsum[i]; wsum[i] = run; run += t; }
    }
    __syncthreads();
    int texcl = x - s + wsum[wid];
#pragma unroll
    for (int i = 0; i < CH; ++i) {
        int idx = base + i;
        if (idx < PH) bh[idx] = texcl + vals[i];
    }
}

__global__ void permscatter_kernel(const int* __restrict__ degarr, const int* __restrict__ bh,
                                   int* __restrict__ perm) {
    __shared__ int lh[64];
    __shared__ int lbase[64];
    if (threadIdx.x < 64) {
        lh[threadIdx.x] = 0;
        lbase[threadIdx.x] = bh[threadIdx.x * NB + blockIdx.x];
    }
    __syncthreads();
    int gid = blockIdx.x * 256 + threadIdx.x;
    if (gid < NN) {
        int b = min(degarr[gid], 63);
        int r = atomicAdd(&lh[b], 1);
        perm[lbase[b] + r] = gid;
    }
}

// fused 8B scatter into chunk-ordered slot: edge2[pos] = {src, bits(dinv[s]*dinv[d])}
__global__ void fill_kernel(const int* __restrict__ src, const int* __restrict__ dst,
                            int* __restrict__ next_pos2, const float* __restrict__ dinv,
                            int2* __restrict__ edge2) {
    int e = blockIdx.x * 256 + threadIdx.x;
    if (e < NE) {
        int s = src[e], d = dst[e];
        int pos = atomicAdd(&next_pos2[d * NCH + s / CHSZ], 1);
        int2 o;
        o.x = s;
        o.y = __float_as_int(dinv[s] * dinv[d]);
        edge2[pos] = o;
    }
}

// ---------------- casts ----------------

__global__ void cast_kernel(const float* __restrict__ in, ushort* __restrict__ outb) {
    int i = blockIdx.x * 256 + threadIdx.x;
    float2 v = ((const float2*)in)[i];
    ushort2 o;
    o.x = f2bf_bits(v.x);
    o.y = f2bf_bits(v.y);
    ((ushort2*)outb)[i] = o;
}

__global__ void wtcast_kernel(const float* __restrict__ W, ushort* __restrict__ Wt) {
    int i = blockIdx.x * 256 + threadIdx.x;  // 3*128*128 = 49152
    int l = i >> 14, k = (i >> 7) & 127, n = i & 127;
    Wt[l * 16384 + n * 128 + k] = f2bf_bits(W[i]);
}

// ---------------- per-layer: aggregate (pre-GEMM, linearity), bf16 gather ----------------
__device__ inline void accum8(float* acc, uint4 v, float w) {
    uint vv[4] = {v.x, v.y, v.z, v.w};
#pragma unroll
    for (int i = 0; i < 4; ++i) {
        float lo = __uint_as_float(vv[i] << 16);
        float hi = __uint_as_float(vv[i] & 0xffff0000u);
        acc[2 * i] = fmaf(w, lo, acc[2 * i]);
        acc[2 * i + 1] = fmaf(w, hi, acc[2 * i + 1]);
    }
}

// 4 nodes/wave (16 lanes x 16B each), degree-balanced via perm, x4 unrolled gather.
// Rows are chunk-sorted, so phase-aligned waves keep the live slice L2-resident.
__global__ __launch_bounds__(256) void agg_kernel(
    const ushort* __restrict__ curb, const int* __restrict__ row_ptr,
    const int2* __restrict__ edge2, const int* __restrict__ perm,
    const float* __restrict__ dinv, ushort* __restrict__ aggb) {
    int wavei = threadIdx.x >> 6;
    int lane = threadIdx.x & 63;
    int g = lane >> 4, t = lane & 15;
    int slot = blockIdx.x * 16 + wavei * 4 + g;  // grid 3125*16 = 50000 exact
    int node = perm[slot];
    int beg = row_ptr[node], end = row_ptr[node + 1];
    const uint4* cu4 = (const uint4*)curb;
    float acc[8] = {};
    int e = beg;
    for (; e + 4 <= end; e += 4) {
        int2 a0 = edge2[e + 0];
        int2 a1 = edge2[e + 1];
        int2 a2 = edge2[e + 2];
        int2 a3 = edge2[e + 3];
        uint4 v0 = cu4[a0.x * 16 + t];
        uint4 v1 = cu4[a1.x * 16 + t];
        uint4 v2 = cu4[a2.x * 16 + t];
        uint4 v3 = cu4[a3.x * 16 + t];
        accum8(acc, v0, __int_as_float(a0.y));
        accum8(acc, v1, __int_as_float(a1.y));
        accum8(acc, v2, __int_as_float(a2.y));
        accum8(acc, v3, __int_as_float(a3.y));
    }
    for (; e < end; ++e) {
        int2 a = edge2[e];
        accum8(acc, cu4[a.x * 16 + t], __int_as_float(a.y));
    }
    float di = dinv[node];
    accum8(acc, cu4[node * 16 + t], di * di);
    union { ushort us[8]; uint4 u; } pk;
#pragma unroll
    for (int i = 0; i < 8; ++i) pk.us[i] = f2bf_bits(acc[i]);
    ((uint4*)aggb)[node * 16 + t] = pk.u;
}

// ---------------- per-layer: MFMA GEMM + bias + LayerNorm + ReLU + residual ----------------
// Block 256 = 4 waves, 64 rows. LDS: Wt 128x17 uint4 + A 64x17 uint4 = 52224B -> 3 blocks/CU.
template <bool RES, bool FINAL>
__global__ __launch_bounds__(256) void gemm_ln_kernel(
    const ushort* __restrict__ aggb, const ushort* __restrict__ Wt,
    const float* __restrict__ bias, const float* __restrict__ gamma,
    const float* __restrict__ beta, ushort* __restrict__ featb, float* __restrict__ out) {
    __shared__ uint4 sB[128 * 17];
    __shared__ uint4 sA[64 * 17];

    const uint4* Wg = (const uint4*)Wt;
    for (int i = threadIdx.x; i < 2048; i += 256) sB[(i >> 4) * 17 + (i & 15)] = Wg[i];

    int row0 = blockIdx.x * 64;
    int nrows = min(64, NN - row0);
    const uint4* Ag = (const uint4*)(aggb + (size_t)row0 * DD);
    for (int i = threadIdx.x; i < nrows * 16; i += 256) sA[(i >> 4) * 17 + (i & 15)] = Ag[i];
    for (int i = nrows * 16 + threadIdx.x; i < 64 * 16; i += 256)
        sA[(i >> 4) * 17 + (i & 15)] = make_uint4(0, 0, 0, 0);
    __syncthreads();

    int w = threadIdx.x >> 6, lane = threadIdx.x & 63;
    int q = lane >> 4, m = lane & 15;

    f32x4 acc[8];
#pragma unroll
    for (int t = 0; t < 8; ++t) acc[t] = (f32x4){0.f, 0.f, 0.f, 0.f};

#pragma unroll
    for (int kk = 0; kk < 4; ++kk) {
        bf16x8 af = *(const bf16x8*)&sA[(16 * w + m) * 17 + kk * 4 + q];
#pragma unroll
        for (int t = 0; t < 8; ++t) {
            bf16x8 bf = *(const bf16x8*)&sB[(16 * t + m) * 17 + kk * 4 + q];
            acc[t] = __builtin_amdgcn_mfma_f32_16x16x32_bf16(af, bf, acc[t], 0, 0, 0);
        }
    }

    float s1[4] = {0.f, 0.f, 0.f, 0.f}, s2[4] = {0.f, 0.f, 0.f, 0.f};
#pragma unroll
    for (int t = 0; t < 8; ++t) {
        float b = bias[16 * t + m];
#pragma unroll
        for (int r = 0; r < 4; ++r) {
            float v = acc[t][r] + b;
            acc[t][r] = v;
            s1[r] += v;
            s2[r] += v * v;
        }
    }
#pragma unroll
    for (int off = 1; off <= 8; off <<= 1) {
#pragma unroll
        for (int r = 0; r < 4; ++r) {
            s1[r] += __shfl_xor(s1[r], off, 64);
            s2[r] += __shfl_xor(s2[r], off, 64);
        }
    }
    float mu[4], rstd[4];
#pragma unroll
    for (int r = 0; r < 4; ++r) {
        mu[r] = s1[r] * (1.f / 128.f);
        float var = s2[r] * (1.f / 128.f) - mu[r] * mu[r];
        rstd[r] = rsqrtf(var + LN_EPS);
    }
    int rowbase = row0 + 16 * w + q * 4;
#pragma unroll
    for (int t = 0; t < 8; ++t) {
        int col = 16 * t + m;
        float ga = gamma[col], be = beta[col];
#pragma unroll
        for (int r = 0; r < 4; ++r) {
            int row = rowbase + r;
            float o = fmaxf((acc[t][r] - mu[r]) * rstd[r] * ga + be, 0.f);
            if (row < NN) {
                size_t idx = (size_t)row * DD + col;
                if (RES) o += __uint_as_float(((uint)featb[idx]) << 16);
                if (FINAL) out[idx] = o;
                else featb[idx] = f2bf_bits(o);
            }
        }
    }
}

// ---------------- launch ----------------

extern "C" void kernel_launch(void* const* d_in, const int* in_sizes, int n_in,
                              void* d_out, int out_size, void* d_ws, size_t ws_size,
                              hipStream_t stream) {
    const float* x = (const float*)d_in[0];
    const int* edge = (const int*)d_in[1];
    const float* Ws = (const float*)d_in[2];
    const float* bs = (const float*)d_in[3];
    const float* gs = (const float*)d_in[4];
    const float* bes = (const float*)d_in[5];
    float* out = (float*)d_out;
    const int* src = edge;
    const int* dst = edge + NE;

    char* p = (char*)d_ws;
    int* counts2 = (int*)p;     p += (size_t)NC2 * 4;     // scanned in place
    int* bsums = (int*)p;       p += 1024 * 4;
    int* row_ptr = (int*)p;     p += (size_t)(NN + 4) * 4;
    int* next_pos2 = (int*)p;   p += (size_t)NC2 * 4;
    float* dinv = (float*)p;    p += (size_t)NN * 4;
    int* degarr = (int*)p;      p += (size_t)NN * 4;
    int* bh = (int*)p;          p += (size_t)PH * 4;
    int* perm = (int*)p;        p += (size_t)NN * 4;
    int2* edge2 = (int2*)p;     p += (size_t)NE * 8;
    ushort* aggb = (ushort*)p;  p += (size_t)NN * DD * 2;
    ushort* featb = (ushort*)p; p += (size_t)NN * DD * 2;
    ushort* Wt = (ushort*)p;    p += (size_t)3 * DD * DD * 2;

    hipMemsetAsync(counts2, 0, (size_t)NC2 * 4, stream);
    hist_kernel<<<NE / 256, 256, 0, stream>>>(src, dst, counts2);
    scan1024_blocks<<<NSB, 1024, 0, stream>>>(counts2, bsums);
    scan_sums1024<<<1, 1024, 0, stream>>>(bsums, NSB);
    finalize_kernel<<<NB, 256, 0, stream>>>(counts2, bsums, row_ptr, next_pos2, dinv, degarr);
    blockhist_kernel<<<NB, 256, 0, stream>>>(degarr, bh);
    permscan_kernel<<<1, 1024, 0, stream>>>(bh);
    permscatter_kernel<<<NB, 256, 0, stream>>>(degarr, bh, perm);
    fill_kernel<<<NE / 256, 256, 0, stream>>>(src, dst, next_pos2, dinv, edge2);

    wtcast_kernel<<<192, 256, 0, stream>>>(Ws, Wt);
    cast_kernel<<<NN * 64 / 256, 256, 0, stream>>>(x, featb);

    int gemm_grid = (NN + 63) / 64;  // 782
    for (int l = 0; l < 3; ++l) {
        agg_kernel<<<NN / 16, 256, 0, stream>>>(featb, row_ptr, edge2, perm, dinv, aggb);
        const ushort* Wl = Wt + (size_t)l * DD * DD;
        const float* bl = bs + l * DD;
        const float* gl = gs + l * DD;
        const float* bel = bes + l * DD;
        if (l == 0)
            gemm_ln_kernel<false, false><<<gemm_grid, 256, 0, stream>>>(
                aggb, Wl, bl, gl, bel, featb, out);
        else if (l == 1)
            gemm_ln_kernel<true, false><<<gemm_grid, 256, 0, stream>>>(
                aggb, Wl, bl, gl, bel, featb, out);
        else
            gemm_ln_kernel<true, true><<<gemm_grid, 256, 0, stream>>>(
                aggb, Wl, bl, gl, bel, featb, out);
    }
}

// Round 7
// 312.889 us; speedup vs baseline: 1.5440x; 1.1916x over previous
//
#include <hip/hip_runtime.h>
#include <hip/hip_bf16.h>

#define NN 50000
#define NE 800000
#define DD 128
#define NB 196             // ceil(NN/256)
#define NCH 8              // source chunks (1.6 MB bf16 slice each)
#define CHSZ 6250          // NN / NCH
#define NC2 (NN * NCH)     // per-(node,chunk) bins = 400000
#define NSB 391            // ceil(NC2/1024)
#define PH (64 * NB)       // degree-bucket histogram size = 12544
#define FS 2048            // fill: edges per slice
#define NSL 391            // ceil(NE/FS)
#define HB 3125            // hist blocks (NE/256)
#define CB 3125            // cast blocks (NN*DD/8/256)
#define WB 192             // wtcast blocks
#define LN_EPS 1e-5f

typedef __bf16 bf16x8 __attribute__((ext_vector_type(8)));
typedef float f32x4 __attribute__((ext_vector_type(4)));

__device__ inline ushort f2bf_bits(float f) {
    union { __hip_bfloat16 h; ushort u; } c;
    c.h = __float2bfloat16(f);
    return c.u;
}

// ---------------- fused: per-(dst,chunk) histogram + feature cast + Wt cast ----------------
__global__ void hist_cast_kernel(const int* __restrict__ src, const int* __restrict__ dst,
                                 int* __restrict__ counts2, const float* __restrict__ x,
                                 uint4* __restrict__ fb0, const float* __restrict__ W,
                                 ushort* __restrict__ Wt) {
    int b = blockIdx.x;
    if (b < HB) {
        int e = b * 256 + threadIdx.x;
        int s = src[e], d = dst[e];
        atomicAdd(&counts2[d * NCH + s / CHSZ], 1);
    } else if (b < HB + CB) {
        int i = (b - HB) * 256 + threadIdx.x;  // 800000 threads x 8 floats
        float4 v0 = ((const float4*)x)[2 * i];
        float4 v1 = ((const float4*)x)[2 * i + 1];
        union { ushort us[8]; uint4 u; } pk;
        pk.us[0] = f2bf_bits(v0.x); pk.us[1] = f2bf_bits(v0.y);
        pk.us[2] = f2bf_bits(v0.z); pk.us[3] = f2bf_bits(v0.w);
        pk.us[4] = f2bf_bits(v1.x); pk.us[5] = f2bf_bits(v1.y);
        pk.us[6] = f2bf_bits(v1.z); pk.us[7] = f2bf_bits(v1.w);
        fb0[i] = pk.u;
    } else {
        int i = (b - HB - CB) * 256 + threadIdx.x;  // 3*128*128 = 49152
        int l = i >> 14, k = (i >> 7) & 127, n = i & 127;
        Wt[l * 16384 + n * 128 + k] = f2bf_bits(W[i]);
    }
}

// level-0 scan over NC2 elements, 1024 threads/block, in-place; emits block sums
__global__ __launch_bounds__(1024) void scan1024_blocks(int* __restrict__ data,
                                                        int* __restrict__ bsums) {
    __shared__ int ws[16];
    int gid = blockIdx.x * 1024 + threadIdx.x;
    int lane = threadIdx.x & 63, wid = threadIdx.x >> 6;
    int v = (gid < NC2) ? data[gid] : 0;
    int x = v;
#pragma unroll
    for (int off = 1; off < 64; off <<= 1) {
        int t = __shfl_up(x, off, 64);
        if (lane >= off) x += t;
    }
    if (lane == 63) ws[wid] = x;
    __syncthreads();
    if (threadIdx.x == 0) {
        int run = 0;
        for (int i = 0; i < 16; ++i) { int t = ws[i]; ws[i] = run; run += t; }
        bsums[blockIdx.x] = run;
    }
    __syncthreads();
    if (gid < NC2) data[gid] = x - v + ws[wid];
}

// level-1: single block scans the 391 block sums
__global__ __launch_bounds__(1024) void scan_sums1024(int* __restrict__ bsums, int nb) {
    __shared__ int ws[16];
    int tid = threadIdx.x;
    int lane = tid & 63, wid = tid >> 6;
    int v = (tid < nb) ? bsums[tid] : 0;
    int x = v;
#pragma unroll
    for (int off = 1; off < 64; off <<= 1) {
        int t = __shfl_up(x, off, 64);
        if (lane >= off) x += t;
    }
    if (lane == 63) ws[wid] = x;
    __syncthreads();
    if (tid == 0) {
        int run = 0;
        for (int i = 0; i < 16; ++i) { int t = ws[i]; ws[i] = run; run += t; }
    }
    __syncthreads();
    if (tid < nb) bsums[tid] = x - v + ws[wid];
}

// absolute cursors, row_ptr, degree, dinv + fused per-block degree histogram
__global__ void finalize_kernel(const int* __restrict__ excl2, const int* __restrict__ bsums,
                                int* __restrict__ row_ptr, int* __restrict__ next_pos2,
                                float* __restrict__ dinv, int* __restrict__ degarr,
                                int* __restrict__ bh) {
    __shared__ int lh[64];
    if (threadIdx.x < 64) lh[threadIdx.x] = 0;
    __syncthreads();
    int d = blockIdx.x * 256 + threadIdx.x;
    if (d < NN) {
        int base = d * NCH;
        int p0 = excl2[base] + bsums[base >> 10];
#pragma unroll
        for (int c = 0; c < NCH; ++c) {
            int idx = base + c;
            next_pos2[idx] = excl2[idx] + bsums[idx >> 10];
        }
        int nxt = (d == NN - 1) ? NE : excl2[base + NCH] + bsums[(base + NCH) >> 10];
        int deg = nxt - p0;
        row_ptr[d] = p0;
        dinv[d] = rsqrtf((float)deg + 1.0f);
        degarr[d] = deg;
        atomicAdd(&lh[min(deg, 63)], 1);
    }
    __syncthreads();
    if (threadIdx.x < 64) bh[threadIdx.x * NB + blockIdx.x] = lh[threadIdx.x];
    if (blockIdx.x == 0 && threadIdx.x == 0) row_ptr[NN] = NE;
}

__global__ __launch_bounds__(1024) void permscan_kernel(int* __restrict__ bh) {
    __shared__ int wsum[16];
    const int CH = 13;  // 1024*13 = 13312 >= 12544
    int tid = threadIdx.x;
    int base = tid * CH;
    int vals[CH];
    int s = 0;
#pragma unroll
    for (int i = 0; i < CH; ++i) {
        int idx = base + i;
        int v = (idx < PH) ? bh[idx] : 0;
        vals[i] = s;
        s += v;
    }
    int lane = tid & 63, wid = tid >> 6;
    int x = s;
#pragma unroll
    for (int off = 1; off < 64; off <<= 1) {
        int t = __shfl_up(x, off, 64);
        if (lane >= off) x += t;
    }
    if (lane == 63) wsum[wid] = x;
    __syncthreads();
    if (tid == 0) {
        int run = 0;
        for (int i = 0; i < 16; ++i) { int t = wsum[i]; wsum[i] = run; run += t; }
    }
    __syncthreads();
    int texcl = x - s + wsum[wid];
#pragma unroll
    for (int i = 0; i < CH; ++i) {
        int idx = base + i;
        if (idx < PH) bh[idx] = texcl + vals[i];
    }
}

__global__ void permscatter_kernel(const int* __restrict__ degarr, const int* __restrict__ bh,
                                   int* __restrict__ perm) {
    __shared__ int lh[64];
    __shared__ int lbase[64];
    if (threadIdx.x < 64) {
        lh[threadIdx.x] = 0;
        lbase[threadIdx.x] = bh[threadIdx.x * NB + blockIdx.x];
    }
    __syncthreads();
    int gid = blockIdx.x * 256 + threadIdx.x;
    if (gid < NN) {
        int b = min(degarr[gid], 63);
        int r = atomicAdd(&lh[b], 1);
        perm[lbase[b] + r] = gid;
    }
}

// XCD-partitioned fill: block b scans edge slice (b>>3), handles only dst range (b&7).
// With blockIdx%8 -> XCD round-robin, each edge2 region is written by ONE XCD,
// so 64B lines coalesce in that L2 instead of bouncing (R6: 54MB writes = 1 line/edge).
__global__ void fill_kernel(const int* __restrict__ src, const int* __restrict__ dst,
                            int* __restrict__ next_pos2, const float* __restrict__ dinv,
                            int2* __restrict__ edge2) {
    int slice = blockIdx.x >> 3;
    int r = blockIdx.x & 7;
    int base = slice * FS;
#pragma unroll 2
    for (int i = threadIdx.x; i < FS; i += 256) {
        int e = base + i;
        if (e < NE) {
            int d = dst[e];
            if (d / CHSZ == r) {
                int s = src[e];
                int pos = atomicAdd(&next_pos2[d * NCH + s / CHSZ], 1);
                int2 o;
                o.x = s;
                o.y = __float_as_int(dinv[s] * dinv[d]);
                edge2[pos] = o;
            }
        }
    }
}

// ---------------- fused per-layer: gather-aggregate + MFMA GEMM + bias+LN+ReLU+residual ----
// Block 256 = 4 waves = 16 nodes (one 16-row MFMA tile). Gather packs bf16 rows straight
// into the LDS A-tile; B-fragments come from global Wt (32KB, L2-hot). Ping-pong feature
// buffers make cross-block gather-read vs epilogue-write race-free.
template <bool RES, bool FINAL>
__global__ __launch_bounds__(256) void layer_kernel(
    const ushort* __restrict__ fin, const int* __restrict__ row_ptr,
    const int2* __restrict__ edge2, const int* __restrict__ perm,
    const float* __restrict__ dinv, const ushort* __restrict__ Wt,
    const float* __restrict__ bias, const float* __restrict__ gamma,
    const float* __restrict__ beta, ushort* __restrict__ fout, float* __restrict__ out) {
    __shared__ uint4 sA[16 * 17];
    __shared__ int sNode[16];
    __shared__ float sLN1[4][16], sLN2[4][16];

    int w = threadIdx.x >> 6, lane = threadIdx.x & 63;
    int g = lane >> 4, t = lane & 15;
    int arow = w * 4 + g;
    int slot = blockIdx.x * 16 + arow;  // grid 3125*16 = 50000 exact
    int node = perm[slot];
    if (t == 0) sNode[arow] = node;

    // ---- phase 1: gather-aggregate (16 lanes x 16B per node row) ----
    {
        int beg = row_ptr[node], end = row_ptr[node + 1];
        const uint4* cu4 = (const uint4*)fin;
        float acc[8] = {};
        int e = beg;
        for (; e + 4 <= end; e += 4) {
            int2 a0 = edge2[e + 0];
            int2 a1 = edge2[e + 1];
            int2 a2 = edge2[e + 2];
            int2 a3 = edge2[e + 3];
            uint4 v0 = cu4[a0.x * 16 + t];
            uint4 v1 = cu4[a1.x * 16 + t];
            uint4 v2 = cu4[a2.x * 16 + t];
            uint4 v3 = cu4[a3.x * 16 + t];
            uint vv0[4] = {v0.x, v0.y, v0.z, v0.w};
            uint vv1[4] = {v1.x, v1.y, v1.z, v1.w};
            uint vv2[4] = {v2.x, v2.y, v2.z, v2.w};
            uint vv3[4] = {v3.x, v3.y, v3.z, v3.w};
            float w0 = __int_as_float(a0.y), w1 = __int_as_float(a1.y);
            float w2 = __int_as_float(a2.y), w3 = __int_as_float(a3.y);
#pragma unroll
            for (int i = 0; i < 4; ++i) {
                acc[2 * i] = fmaf(w0, __uint_as_float(vv0[i] << 16), acc[2 * i]);
                acc[2 * i + 1] = fmaf(w0, __uint_as_float(vv0[i] & 0xffff0000u), acc[2 * i + 1]);
                acc[2 * i] = fmaf(w1, __uint_as_float(vv1[i] << 16), acc[2 * i]);
                acc[2 * i + 1] = fmaf(w1, __uint_as_float(vv1[i] & 0xffff0000u), acc[2 * i + 1]);
                acc[2 * i] = fmaf(w2, __uint_as_float(vv2[i] << 16), acc[2 * i]);
                acc[2 * i + 1] = fmaf(w2, __uint_as_float(vv2[i] & 0xffff0000u), acc[2 * i + 1]);
                acc[2 * i] = fmaf(w3, __uint_as_float(vv3[i] << 16), acc[2 * i]);
                acc[2 * i + 1] = fmaf(w3, __uint_as_float(vv3[i] & 0xffff0000u), acc[2 * i + 1]);
            }
        }
        for (; e < end; ++e) {
            int2 a = edge2[e];
            uint4 v = cu4[a.x * 16 + t];
            uint vv[4] = {v.x, v.y, v.z, v.w};
            float ww = __int_as_float(a.y);
#pragma unroll
            for (int i = 0; i < 4; ++i) {
                acc[2 * i] = fmaf(ww, __uint_as_float(vv[i] << 16), acc[2 * i]);
                acc[2 * i + 1] = fmaf(ww, __uint_as_float(vv[i] & 0xffff0000u), acc[2 * i + 1]);
            }
        }
        float di = dinv[node];
        float w2s = di * di;
        {
            uint4 v = cu4[node * 16 + t];
            uint vv[4] = {v.x, v.y, v.z, v.w};
#pragma unroll
            for (int i = 0; i < 4; ++i) {
                acc[2 * i] = fmaf(w2s, __uint_as_float(vv[i] << 16), acc[2 * i]);
                acc[2 * i + 1] = fmaf(w2s, __uint_as_float(vv[i] & 0xffff0000u), acc[2 * i + 1]);
            }
        }
        union { ushort us[8]; uint4 u; } pk;
#pragma unroll
        for (int i = 0; i < 8; ++i) pk.us[i] = f2bf_bits(acc[i]);
        sA[arow * 17 + t] = pk.u;
    }
    __syncthreads();

    // ---- phase 2: MFMA 16x128 tile; wave w owns col-tiles 2w, 2w+1 ----
    int q = lane >> 4, m = lane & 15;
    f32x4 c0 = (f32x4){0.f, 0.f, 0.f, 0.f};
    f32x4 c1 = (f32x4){0.f, 0.f, 0.f, 0.f};
    int n0 = 16 * (2 * w), n1 = 16 * (2 * w + 1);
#pragma unroll
    for (int kk = 0; kk < 4; ++kk) {
        bf16x8 af = *(const bf16x8*)&sA[m * 17 + kk * 4 + q];
        bf16x8 b0 = *(const bf16x8*)(Wt + (n0 + m) * DD + kk * 32 + q * 8);
        bf16x8 b1 = *(const bf16x8*)(Wt + (n1 + m) * DD + kk * 32 + q * 8);
        c0 = __builtin_amdgcn_mfma_f32_16x16x32_bf16(af, b0, c0, 0, 0, 0);
        c1 = __builtin_amdgcn_mfma_f32_16x16x32_bf16(af, b1, c1, 0, 0, 0);
    }

    // ---- epilogue: bias + LN (in-wave m-reduce, LDS cross-wave combine) + ReLU + res ----
    float bb0 = bias[n0 + m], bb1 = bias[n1 + m];
    float s1[4], s2[4];
#pragma unroll
    for (int r = 0; r < 4; ++r) {
        float v0 = c0[r] + bb0, v1 = c1[r] + bb1;
        c0[r] = v0; c1[r] = v1;
        s1[r] = v0 + v1;
        s2[r] = v0 * v0 + v1 * v1;
    }
#pragma unroll
    for (int off = 1; off <= 8; off <<= 1) {
#pragma unroll
        for (int r = 0; r < 4; ++r) {
            s1[r] += __shfl_xor(s1[r], off, 64);
            s2[r] += __shfl_xor(s2[r], off, 64);
        }
    }
    if (m == 0) {
#pragma unroll
        for (int r = 0; r < 4; ++r) {
            sLN1[w][q * 4 + r] = s1[r];
            sLN2[w][q * 4 + r] = s2[r];
        }
    }
    __syncthreads();
    float ga0 = gamma[n0 + m], ga1 = gamma[n1 + m];
    float be0 = beta[n0 + m], be1 = beta[n1 + m];
#pragma unroll
    for (int r = 0; r < 4; ++r) {
        int row = q * 4 + r;
        float S1 = sLN1[0][row] + sLN1[1][row] + sLN1[2][row] + sLN1[3][row];
        float S2 = sLN2[0][row] + sLN2[1][row] + sLN2[2][row] + sLN2[3][row];
        float mu = S1 * (1.f / 128.f);
        float var = S2 * (1.f / 128.f) - mu * mu;
        float rstd = rsqrtf(var + LN_EPS);
        int nd = sNode[row];
        size_t rb = (size_t)nd * DD;
        float o0 = fmaxf((c0[r] - mu) * rstd * ga0 + be0, 0.f);
        float o1 = fmaxf((c1[r] - mu) * rstd * ga1 + be1, 0.f);
        if (RES) {
            o0 += __uint_as_float(((uint)fin[rb + n0 + m]) << 16);
            o1 += __uint_as_float(((uint)fin[rb + n1 + m]) << 16);
        }
        if (FINAL) {
            out[rb + n0 + m] = o0;
            out[rb + n1 + m] = o1;
        } else {
            fout[rb + n0 + m] = f2bf_bits(o0);
            fout[rb + n1 + m] = f2bf_bits(o1);
        }
    }
}

// ---------------- launch ----------------

extern "C" void kernel_launch(void* const* d_in, const int* in_sizes, int n_in,
                              void* d_out, int out_size, void* d_ws, size_t ws_size,
                              hipStream_t stream) {
    const float* x = (const float*)d_in[0];
    const int* edge = (const int*)d_in[1];
    const float* Ws = (const float*)d_in[2];
    const float* bs = (const float*)d_in[3];
    const float* gs = (const float*)d_in[4];
    const float* bes = (const float*)d_in[5];
    float* out = (float*)d_out;
    const int* src = edge;
    const int* dst = edge + NE;

    char* p = (char*)d_ws;
    int* counts2 = (int*)p;     p += (size_t)NC2 * 4;     // scanned in place
    int* bsums = (int*)p;       p += 1024 * 4;
    int* row_ptr = (int*)p;     p += (size_t)(NN + 4) * 4;
    int* next_pos2 = (int*)p;   p += (size_t)NC2 * 4;
    float* dinv = (float*)p;    p += (size_t)NN * 4;
    int* degarr = (int*)p;      p += (size_t)NN * 4;
    int* bh = (int*)p;          p += (size_t)PH * 4;
    int* perm = (int*)p;        p += (size_t)NN * 4;
    int2* edge2 = (int2*)p;     p += (size_t)NE * 8;
    ushort* fb0 = (ushort*)p;   p += (size_t)NN * DD * 2;
    ushort* fb1 = (ushort*)p;   p += (size_t)NN * DD * 2;
    ushort* Wt = (ushort*)p;    p += (size_t)3 * DD * DD * 2;

    hipMemsetAsync(counts2, 0, (size_t)NC2 * 4, stream);
    hist_cast_kernel<<<HB + CB + WB, 256, 0, stream>>>(src, dst, counts2, x, (uint4*)fb0, Ws,
                                                       Wt);
    scan1024_blocks<<<NSB, 1024, 0, stream>>>(counts2, bsums);
    scan_sums1024<<<1, 1024, 0, stream>>>(bsums, NSB);
    finalize_kernel<<<NB, 256, 0, stream>>>(counts2, bsums, row_ptr, next_pos2, dinv, degarr,
                                            bh);
    permscan_kernel<<<1, 1024, 0, stream>>>(bh);
    permscatter_kernel<<<NB, 256, 0, stream>>>(degarr, bh, perm);
    fill_kernel<<<NSL * 8, 256, 0, stream>>>(src, dst, next_pos2, dinv, edge2);

    int lg = NN / 16;  // 3125
    layer_kernel<false, false><<<lg, 256, 0, stream>>>(
        fb0, row_ptr, edge2, perm, dinv, Wt, bs, gs, bes, fb1, out);
    layer_kernel<true, false><<<lg, 256, 0, stream>>>(
        fb1, row_ptr, edge2, perm, dinv, Wt + 16384, bs + DD, gs + DD, bes + DD, fb0, out);
    layer_kernel<true, true><<<lg, 256, 0, stream>>>(
        fb0, row_ptr, edge2, perm, dinv, Wt + 32768, bs + 2 * DD, gs + 2 * DD, bes + 2 * DD,
        fb1, out);
}